// Round 12
// baseline (110.862 us; speedup 1.0000x reference)
//
#include <hip/hip_runtime.h>
#include <hip/hip_bf16.h>
#include <stdint.h>
#include <stddef.h>

#define TM 16      // output rows per block
#define CIN 64     // C_in
#define NK3 27     // K3 neighbors
#define NK3P 28    // padded to even (kc=27 contributes zero)
#define COUT 128   // C_out
#define EPS_LN 1e-3f
#define KCH  (NK3 * CIN / 32)    // 54 real k-chunks of 32
#define KCHP (NK3P * CIN / 32)   // 56 padded k-chunks
#define NT   (COUT / 16)         // 8 column tiles (one per wave)
#define NPAIR (NK3P / 2)         // 14 kc-pairs
#define PK_BYTES (NT * KCHP * 64 * 8 * 2)   // 458752

typedef __attribute__((ext_vector_type(8))) short   short8;   // MFMA A/B frag (8 bf16)
typedef __attribute__((ext_vector_type(4))) float   floatx4;  // MFMA C/D frag
typedef __attribute__((ext_vector_type(4))) unsigned short ushort4v;

__device__ __forceinline__ unsigned short f2b(float f) {
    union { float f; unsigned int i; } v;
    v.f = f;
    unsigned int i = v.i; // RNE bf16
    return (unsigned short)((i + 0x7fffu + ((i >> 16) & 1u)) >> 16);
}

// ---- kernel 1: pack W -> bf16 B-fragments (zero-padded) + one-time dtype probe ----
__global__ __launch_bounds__(256) void pack_w(const float* __restrict__ Wm,
                                              const int* __restrict__ voxel_idx,
                                              const int* __restrict__ num_list,
                                              int Bc,
                                              unsigned short* __restrict__ pk,
                                              int* __restrict__ flags) {
    const int t = threadIdx.x;
    if (blockIdx.x == 0 && t < 64) {
        int wv = voxel_idx[2 * t + 1];
        unsigned long long nz = __ballot(wv != 0);
        if (t == 0) {
            int f = (nz == 0ULL) ? 1 : 0;     // int64 voxel_idx -> odd words all zero
            bool n64 = false;
            if (Bc >= 2) {
                n64 = (num_list[1] == 0) && (num_list[0] != 0);
                if (Bc >= 4) n64 = n64 && (num_list[3] == 0);
            }
            if (n64) f |= 2;
            flags[0] = f;
        }
    }
    int slot = blockIdx.x * 256 + t;             // 0 .. NT*KCHP*64-1
    int l  = slot & 63;
    int kk = (slot >> 6) % KCHP;
    int nt = slot / (64 * KCHP);
    short8 v = {0, 0, 0, 0, 0, 0, 0, 0};
    if (kk < KCH) {
        int q = l >> 4, n = l & 15;
        const float* src = Wm + (size_t)(kk * 32 + q * 8) * COUT + nt * 16 + n;
        #pragma unroll
        for (int j = 0; j < 8; ++j)
            v[j] = (short)f2b(src[(size_t)j * COUT]);
    }
    *(short8*)(pk + (size_t)slot * 8) = v;
}

// ---- kernel 2: one-shot A-panel staging, barrier-free MFMA K-loop ----
__global__ __launch_bounds__(512, 4) void dpc_mfma(
    const float* __restrict__ features,   // fp32 [N][CIN]
    const float* __restrict__ center,     // fp32 [M][3]
    const int* __restrict__ voxel_idx,    // int32/int64 (flags)
    const int* __restrict__ num_list,     // int32/int64 (flags)
    const unsigned short* __restrict__ pk,
    const int* __restrict__ flags,
    const float* __restrict__ gamma_,
    const float* __restrict__ beta_,
    float* __restrict__ out_feat,         // fp32 [Rtot][COUT]
    float* __restrict__ out_coor,         // fp32 [Rtot][4]
    int N, int M, int B, int K, int Rtot)
{
    __shared__ int s_vid[TM][NK3P];
    __shared__ int s_src[TM];
    __shared__ int s_valid[TM];
    __shared__ __align__(16) unsigned short s_a[NK3P * 1024]; // full A-panel, frag order
    __shared__ float s_c[TM][COUT + 4];

    const int t  = threadIdx.x;
    const int R0 = blockIdx.x * TM;

    const int fl = flags[0];              // uniform scalar load
    const bool vidx64 = (fl & 1) != 0;
    const bool nl64   = (fl & 2) != 0;

    // ---- preamble: per-row source index + validity ----
    if (t < TM) {
        int r = R0 + t;
        int src = 0, valid = 0;
        if (r < Rtot) {
            int b = r / K;
            int j = r - b * K;
            int offs = 0, nlb = 0;
            for (int i = 0; i < B; ++i) {
                int v = nl64 ? num_list[2 * i] : num_list[i];
                if (i < b) offs += v;
                if (i == b) nlb = v;
            }
            int end = nlb < K ? nlb : K;
            valid = (j < end) ? 1 : 0;
            src = offs + j;
            if (src < 0) src = 0;
            if (src > M - 1) src = M - 1;
        }
        s_src[t] = src;
        s_valid[t] = valid;
    }
    __syncthreads();

    // ---- coords output ----
    if (t < TM * 4) {
        int i = t >> 2, comp = t & 3;
        int r = R0 + i;
        if (r < Rtot) {
            float val;
            if (comp == 0) {
                int b = r / K;
                val = (b < B - 1) ? (float)(b + 1) : 0.0f;
            } else {
                val = s_valid[i] ? center[(size_t)s_src[i] * 3 + comp - 1] : 0.0f;
            }
            out_coor[(size_t)r * 4 + comp] = val;
        }
    }

    // ---- stage voxel ids (pad kc=27 with -1 -> zero A fragment) ----
    for (int lin = t; lin < TM * NK3P; lin += 512) {
        int i = lin / NK3P;
        int k = lin - i * NK3P;
        int v = -1;
        if (k < NK3) {
            size_t e = (size_t)s_src[i] * NK3 + k;
            v = vidx64 ? voxel_idx[2 * e] : voxel_idx[e];
        }
        s_vid[i][k] = v;
    }
    __syncthreads();

    // ---- one-shot A-panel gather: 14 independent loads per thread ----
    const int sub = t >> 8;               // which kc of each pair (0/1)
    const int rem = t & 255;
    const int m   = rem >> 4;             // row 0..15
    const int c0  = (rem & 15) * 4;       // cin col base
    const int chunk = c0 >> 5;
    const int q4    = (c0 & 31) >> 3;
    const int j0    = c0 & 7;
    const int abase = chunk * 512 + (q4 * 16 + m) * 8 + j0;  // within-slab offset

    auto gatherKc = [&](int kc) -> float4 {
        int idx = s_vid[m][kc];
        float4 r = make_float4(0.f, 0.f, 0.f, 0.f);
        if (idx >= 0) {
            if (idx > N - 1) idx = N - 1;
            r = *(const float4*)(features + (size_t)idx * CIN + c0);
        }
        return r;
    };
    auto stashKc = [&](int kc, float4 v) {
        ushort4v u;
        u[0] = f2b(v.x); u[1] = f2b(v.y); u[2] = f2b(v.z); u[3] = f2b(v.w);
        *(ushort4v*)&s_a[kc * 1024 + abase] = u;
    };

    {
        float4 g0_, g1_, g2_, g3_, g4_, g5_, g6_;
        // half-burst 1: kc = sub, 2+sub, ..., 12+sub (7-deep MLP)
        g0_ = gatherKc(sub);      g1_ = gatherKc(2 + sub);  g2_ = gatherKc(4 + sub);
        g3_ = gatherKc(6 + sub);  g4_ = gatherKc(8 + sub);  g5_ = gatherKc(10 + sub);
        g6_ = gatherKc(12 + sub);
        stashKc(sub, g0_);        stashKc(2 + sub, g1_);    stashKc(4 + sub, g2_);
        stashKc(6 + sub, g3_);    stashKc(8 + sub, g4_);    stashKc(10 + sub, g5_);
        stashKc(12 + sub, g6_);
        // half-burst 2: kc = 14+sub .. 26+sub
        g0_ = gatherKc(14 + sub); g1_ = gatherKc(16 + sub); g2_ = gatherKc(18 + sub);
        g3_ = gatherKc(20 + sub); g4_ = gatherKc(22 + sub); g5_ = gatherKc(24 + sub);
        g6_ = gatherKc(26 + sub);
        stashKc(14 + sub, g0_);   stashKc(16 + sub, g1_);   stashKc(18 + sub, g2_);
        stashKc(20 + sub, g3_);   stashKc(22 + sub, g4_);   stashKc(24 + sub, g5_);
        stashKc(26 + sub, g6_);
    }
    __syncthreads();   // the ONLY barrier between staging and compute

    // ---- barrier-free MFMA K-loop: wave w owns col tile nt = w ----
    const int w    = t >> 6;
    const int lane = t & 63;
    auto loadB = [&](int kk) -> short8 {
        return *(const short8*)(pk + ((size_t)(w * KCHP + kk) * 64 + lane) * 8);
    };

    floatx4 acc = {0.f, 0.f, 0.f, 0.f};
    short8 bb0 = loadB(0), bb1 = loadB(1), bb2 = loadB(2), bb3 = loadB(3);

    for (int p = 0; p < NPAIR; ++p) {
        short8 nb0, nb1, nb2, nb3;
        const bool hn = (p + 1 < NPAIR);
        if (hn) {
            const int kk = 4 * (p + 1);
            nb0 = loadB(kk); nb1 = loadB(kk + 1); nb2 = loadB(kk + 2); nb3 = loadB(kk + 3);
        }
        const int base = p * 2048;
        const short8 a0 = *(const short8*)&s_a[base +        lane * 8];
        const short8 a1 = *(const short8*)&s_a[base +  512 + lane * 8];
        const short8 a2 = *(const short8*)&s_a[base + 1024 + lane * 8];
        const short8 a3 = *(const short8*)&s_a[base + 1536 + lane * 8];

        acc = __builtin_amdgcn_mfma_f32_16x16x32_bf16(a0, bb0, acc, 0, 0, 0);
        acc = __builtin_amdgcn_mfma_f32_16x16x32_bf16(a1, bb1, acc, 0, 0, 0);
        acc = __builtin_amdgcn_mfma_f32_16x16x32_bf16(a2, bb2, acc, 0, 0, 0);
        acc = __builtin_amdgcn_mfma_f32_16x16x32_bf16(a3, bb3, acc, 0, 0, 0);

        if (hn) { bb0 = nb0; bb1 = nb1; bb2 = nb2; bb3 = nb3; }
    }

    // ---- C -> LDS (C/D layout: col=lane&15, row=(lane>>4)*4+reg) ----
    {
        const int cq = lane >> 4, n = lane & 15;
        #pragma unroll
        for (int reg = 0; reg < 4; ++reg)
            s_c[cq * 4 + reg][w * 16 + n] = acc[reg];
    }
    __syncthreads();

    // ---- fused LayerNorm + ReLU epilogue (2 rows per wave) ----
    const int c2 = lane * 2;
    const float g0  = gamma_[c2];
    const float g1  = gamma_[c2 + 1];
    const float be0 = beta_[c2];
    const float be1 = beta_[c2 + 1];

    #pragma unroll
    for (int i = 0; i < 2; ++i) {
        int row = w * 2 + i;
        float a0 = s_c[row][c2];
        float a1 = s_c[row][c2 + 1];
        float s  = a0 + a1;
        float ss = a0 * a0 + a1 * a1;
        #pragma unroll
        for (int mm = 1; mm < 64; mm <<= 1) {
            s  += __shfl_xor(s,  mm, 64);
            ss += __shfl_xor(ss, mm, 64);
        }
        float mu   = s * (1.0f / COUT);
        float var  = ss * (1.0f / COUT) - mu * mu;
        float rstd = rsqrtf(var + EPS_LN);
        float v0 = (a0 - mu) * rstd * g0 + be0;
        float v1 = (a1 - mu) * rstd * g1 + be1;
        v0 = fmaxf(v0, 0.f);
        v1 = fmaxf(v1, 0.f);
        if (!s_valid[row]) { v0 = 0.f; v1 = 0.f; }
        int r = R0 + row;
        if (r < Rtot) {
            out_feat[(size_t)r * COUT + c2]     = v0;
            out_feat[(size_t)r * COUT + c2 + 1] = v1;
        }
    }
}

extern "C" void kernel_launch(void* const* d_in, const int* in_sizes, int n_in,
                              void* d_out, int out_size, void* d_ws, size_t ws_size,
                              hipStream_t stream) {
    const float* features = (const float*)d_in[0];
    const float* center   = (const float*)d_in[1];
    const int*   vidx     = (const int*)d_in[2];
    const int*   num_list = (const int*)d_in[3];
    const float* Wm       = (const float*)d_in[4];
    const float* gamma_   = (const float*)d_in[5];
    const float* beta_    = (const float*)d_in[6];

    const int B    = in_sizes[3];                 // 4
    const int Cout = in_sizes[5];                 // 128
    const int M    = in_sizes[1] / 3;             // 40000
    const int K3v  = in_sizes[2] / M;             // 27
    const int Cin  = (in_sizes[4] / Cout) / K3v;  // 64
    const int N    = in_sizes[0] / Cin;           // 200000
    const int Rtot = out_size / (Cout + 4);       // 8192
    const int K    = Rtot / B;                    // 2048

    float* out_feat = (float*)d_out;
    float* out_coor = out_feat + (size_t)Rtot * Cout;

    unsigned short* pk = (unsigned short*)d_ws;
    int* flags = (int*)((char*)d_ws + PK_BYTES);

    const int pack_grid = (NT * KCHP * 64) / 256;       // 112
    pack_w<<<dim3(pack_grid), dim3(256), 0, stream>>>(Wm, vidx, num_list, B, pk, flags);

    const int tiles = (Rtot + TM - 1) / TM;             // 512
    dpc_mfma<<<dim3(tiles), dim3(512), 0, stream>>>(
        features, center, vidx, num_list, pk, flags, gamma_, beta_,
        out_feat, out_coor, N, M, B, K, Rtot);
}